// Round 1
// baseline (417.734 us; speedup 1.0000x reference)
//
#include <hip/hip_runtime.h>
#include <hip/hip_bf16.h>
#include <stdint.h>

#define NH 16
#define HD 64
#define H_ 1024
#define S_ 2048
#define B_ 4
#define MROWS 8192  // B_*S_

typedef __attribute__((ext_vector_type(4))) float f32x4;
typedef __attribute__((ext_vector_type(8))) short s16x8;

__device__ __forceinline__ unsigned short f2bf(float x) {
  unsigned int u = __float_as_uint(x);
  u += 0x7fffu + ((u >> 16) & 1u);
  return (unsigned short)(u >> 16);
}
__device__ __forceinline__ unsigned int pack_bf2(float lo, float hi) {
  return (unsigned int)f2bf(lo) | ((unsigned int)f2bf(hi) << 16);
}

__device__ __forceinline__ void ld_lds16(void* lds, const void* g) {
  __builtin_amdgcn_global_load_lds(
      (const __attribute__((address_space(1))) unsigned int*)g,
      (__attribute__((address_space(3))) unsigned int*)lds, 16, 0, 0);
}

// ---------------- fp32 -> bf16 conversion (vectorized) ----------------
__global__ void cvt_bf16_k(const float* __restrict__ src,
                           unsigned short* __restrict__ dst, int n4) {
  int i = blockIdx.x * blockDim.x + threadIdx.x;
  if (i >= n4) return;
  float4 v = reinterpret_cast<const float4*>(src)[i];
  ushort4 o;
  o.x = f2bf(v.x); o.y = f2bf(v.y); o.z = f2bf(v.z); o.w = f2bf(v.w);
  reinterpret_cast<ushort4*>(dst)[i] = o;
}

// ---------------- fused QKV projection GEMM ----------------
// out[z][bh][s][d] bf16, z in {0:Q,1:K,2:V}.  q = X @ W^T + b
// 128x128 tile, BK=32, 4 waves (2x2), 16x16x32 bf16 MFMA, global_load_lds staging.
__global__ __launch_bounds__(256) void qkv_gemm_k(
    const unsigned short* __restrict__ Xb,   // [8192][1024] bf16
    const unsigned short* __restrict__ Wb,   // [3][1024][1024] bf16 (row n, col k)
    const float* __restrict__ bq, const float* __restrict__ bk,
    const float* __restrict__ bv,
    unsigned short* __restrict__ outAll) {
  __shared__ unsigned short As[128 * 32];
  __shared__ unsigned short Bs[128 * 32];
  int z = blockIdx.z;
  const unsigned short* Wp = Wb + (size_t)z * (H_ * H_);
  const float* bias = (z == 0) ? bq : (z == 1) ? bk : bv;
  unsigned short* outp = outAll + (size_t)z * ((size_t)MROWS * H_);
  int m0 = blockIdx.y * 128, n0 = blockIdx.x * 128;
  int tid = threadIdx.x;
  int w = tid >> 6, l = tid & 63;
  int wr = w >> 1, wc = w & 1;
  int g = l >> 4, ln = l & 15;
  f32x4 acc[4][4] = {};
  for (int k0 = 0; k0 < H_; k0 += 32) {
    __syncthreads();
#pragma unroll
    for (int a = 0; a < 2; ++a) {
      int ci = (w * 2 + a) * 64 + l;        // 16B chunk id (of 512)
      int row = ci >> 2, c = ci & 3;        // 4 chunks per 64B row
      ld_lds16(&As[(w * 2 + a) * 512], &Xb[(size_t)(m0 + row) * H_ + k0 + c * 8]);
      ld_lds16(&Bs[(w * 2 + a) * 512], &Wp[(size_t)(n0 + row) * H_ + k0 + c * 8]);
    }
    __syncthreads();
    s16x8 aF[4], bF[4];
#pragma unroll
    for (int mi = 0; mi < 4; ++mi)
      aF[mi] = *reinterpret_cast<const s16x8*>(&As[(wr * 64 + mi * 16 + ln) * 32 + 8 * g]);
#pragma unroll
    for (int ni = 0; ni < 4; ++ni)
      bF[ni] = *reinterpret_cast<const s16x8*>(&Bs[(wc * 64 + ni * 16 + ln) * 32 + 8 * g]);
#pragma unroll
    for (int mi = 0; mi < 4; ++mi)
#pragma unroll
      for (int ni = 0; ni < 4; ++ni)
        acc[mi][ni] = __builtin_amdgcn_mfma_f32_16x16x32_bf16(aF[mi], bF[ni], acc[mi][ni], 0, 0, 0);
  }
  // epilogue: bias add, bf16 store into [bh][s][d]
#pragma unroll
  for (int ni = 0; ni < 4; ++ni) {
    int ncol = n0 + wc * 64 + ni * 16 + ln;
    float bvv = bias[ncol];
    int h = ncol >> 6, d = ncol & 63;
#pragma unroll
    for (int mi = 0; mi < 4; ++mi) {
#pragma unroll
      for (int j = 0; j < 4; ++j) {
        int m = m0 + wr * 64 + mi * 16 + 4 * g + j;
        int b = m >> 11, s = m & 2047;
        outp[((size_t)((b << 4) + h) * S_ + s) * HD + d] = f2bf(acc[mi][ni][j] + bvv);
      }
    }
  }
}

// ---------------- flash attention ----------------
// grid (S/64, B*NH); 256 thr = 4 waves, each wave owns 16 q-rows.
// Swapped QK^T: S^T = mfma(K_frag, Q^T_frag) -> lane's softmax row q = lane&15.
__global__ __launch_bounds__(256) void attn_k(
    const unsigned short* __restrict__ Qh, const unsigned short* __restrict__ Kh,
    const unsigned short* __restrict__ Vh, const float* __restrict__ mask,
    float* __restrict__ out) {
  __shared__ unsigned short Ks[64 * 72];       // [key][d] padded (+8) rows
  __shared__ unsigned short Vt[64 * 72];       // [d][key] padded rows
  __shared__ unsigned short Pl[4 * 16 * 72];   // per-wave P, [q][key] padded
  __shared__ float maskS[64];
  int bh = blockIdx.y;
  int b = bh >> 4, h = bh & 15;
  int tid = threadIdx.x;
  int w = tid >> 6, l = tid & 63;
  int g = l >> 4, ln = l & 15;
  int qbase = blockIdx.x * 64 + w * 16;
  const unsigned short* Qp = Qh + ((size_t)bh * S_ + qbase + ln) * HD;
  s16x8 qf[2];
  qf[0] = *reinterpret_cast<const s16x8*>(Qp + 8 * g);
  qf[1] = *reinterpret_cast<const s16x8*>(Qp + 32 + 8 * g);
  float m_run = -INFINITY, l_run = 0.0f;
  f32x4 ctx[4] = {};
  unsigned short* Pw = &Pl[w * 16 * 72];
  const size_t kvbase = (size_t)bh * S_ * HD;

  for (int k0 = 0; k0 < S_; k0 += 64) {
    __syncthreads();
    // ---- stage K (row-major padded) and V (transposed padded) ----
#pragma unroll
    for (int a = 0; a < 2; ++a) {
      int c = tid + a * 256;
      int row = c >> 3, cc = c & 7;  // row = key, cc = 16B chunk along d
      s16x8 kv = *reinterpret_cast<const s16x8*>(&Kh[kvbase + (size_t)(k0 + row) * HD + cc * 8]);
      *reinterpret_cast<s16x8*>(&Ks[row * 72 + cc * 8]) = kv;
      s16x8 vv = *reinterpret_cast<const s16x8*>(&Vh[kvbase + (size_t)(k0 + row) * HD + cc * 8]);
#pragma unroll
      for (int j = 0; j < 8; ++j)
        Vt[(cc * 8 + j) * 72 + row] = (unsigned short)vv[j];
    }
    if (tid < 64) maskS[tid] = mask[b * S_ + k0 + tid];
    __syncthreads();

    // ---- QK^T (S^T): rows = keys, cols = q ----
    f32x4 sacc[4] = {};
#pragma unroll
    for (int ks = 0; ks < 2; ++ks) {
#pragma unroll
      for (int mt = 0; mt < 4; ++mt) {
        s16x8 kf = *reinterpret_cast<const s16x8*>(&Ks[(mt * 16 + ln) * 72 + ks * 32 + 8 * g]);
        sacc[mt] = __builtin_amdgcn_mfma_f32_16x16x32_bf16(kf, qf[ks], sacc[mt], 0, 0, 0);
      }
    }
    // ---- softmax for this lane's q (= ln); lane holds keys mt*16+4g+r ----
    float p[4][4];
    float mymax = -INFINITY;
#pragma unroll
    for (int mt = 0; mt < 4; ++mt)
#pragma unroll
      for (int r = 0; r < 4; ++r) {
        float v = sacc[mt][r] * 0.125f + maskS[mt * 16 + 4 * g + r];
        p[mt][r] = v;
        mymax = fmaxf(mymax, v);
      }
    mymax = fmaxf(mymax, __shfl_xor(mymax, 16));
    mymax = fmaxf(mymax, __shfl_xor(mymax, 32));
    float m_new = fmaxf(m_run, mymax);
    float alpha = __expf(m_run - m_new);
    float sum = 0.0f;
#pragma unroll
    for (int mt = 0; mt < 4; ++mt)
#pragma unroll
      for (int r = 0; r < 4; ++r) {
        float e = __expf(p[mt][r] - m_new);
        p[mt][r] = e;
        sum += e;
      }
    sum += __shfl_xor(sum, 16);
    sum += __shfl_xor(sum, 32);
    l_run = l_run * alpha + sum;
    m_run = m_new;
    // ---- write P (bf16 pairs) to wave-local LDS: key = 16mt+4g+2rp(+1) ----
#pragma unroll
    for (int mt = 0; mt < 4; ++mt)
#pragma unroll
      for (int rp = 0; rp < 2; ++rp)
        *reinterpret_cast<unsigned int*>(&Pw[ln * 72 + mt * 16 + 4 * g + 2 * rp]) =
            pack_bf2(p[mt][2 * rp], p[mt][2 * rp + 1]);
    // ---- rescale ctx (ctx rows q' = 4g+r; alpha lives at lane ln'=q') ----
    float resc[4];
#pragma unroll
    for (int r = 0; r < 4; ++r)
      resc[r] = __shfl(alpha, (l & 48) + 4 * g + r);
#pragma unroll
    for (int nt = 0; nt < 4; ++nt)
#pragma unroll
      for (int r = 0; r < 4; ++r) ctx[nt][r] *= resc[r];
    // ---- PV: ctx[q][d] += P[q][key] * V[key][d] ----
#pragma unroll
    for (int ks = 0; ks < 2; ++ks) {
      s16x8 pa = *reinterpret_cast<const s16x8*>(&Pw[ln * 72 + ks * 32 + 8 * g]);
#pragma unroll
      for (int nt = 0; nt < 4; ++nt) {
        s16x8 vf = *reinterpret_cast<const s16x8*>(&Vt[(nt * 16 + ln) * 72 + ks * 32 + 8 * g]);
        ctx[nt] = __builtin_amdgcn_mfma_f32_16x16x32_bf16(pa, vf, ctx[nt], 0, 0, 0);
      }
    }
  }
  // ---- normalize and store (coalesced along d) ----
  float inv[4];
#pragma unroll
  for (int r = 0; r < 4; ++r)
    inv[r] = 1.0f / __shfl(l_run, (l & 48) + 4 * g + r);
#pragma unroll
  for (int nt = 0; nt < 4; ++nt) {
#pragma unroll
    for (int r = 0; r < 4; ++r) {
      int q = qbase + 4 * g + r;
      out[((size_t)(b * S_ + q)) * H_ + h * HD + nt * 16 + ln] = ctx[nt][r] * inv[r];
    }
  }
}

extern "C" void kernel_launch(void* const* d_in, const int* in_sizes, int n_in,
                              void* d_out, int out_size, void* d_ws, size_t ws_size,
                              hipStream_t stream) {
  (void)in_sizes; (void)n_in; (void)out_size; (void)ws_size;
  const float* hs = (const float*)d_in[0];
  const float* mask = (const float*)d_in[1];
  const float* Wq = (const float*)d_in[2];
  const float* bq = (const float*)d_in[3];
  const float* Wk = (const float*)d_in[4];
  const float* bk = (const float*)d_in[5];
  const float* Wv = (const float*)d_in[6];
  const float* bv = (const float*)d_in[7];
  float* out = (float*)d_out;

  unsigned short* Xb = (unsigned short*)d_ws;                  // 8M bf16
  unsigned short* Wb = Xb + (size_t)MROWS * H_;                // 3M bf16
  unsigned short* QKVh = Wb + (size_t)3 * H_ * H_;             // 3 x 8M bf16

  cvt_bf16_k<<<(MROWS * H_ / 4 + 255) / 256, 256, 0, stream>>>(hs, Xb, MROWS * H_ / 4);
  cvt_bf16_k<<<(H_ * H_ / 4 + 255) / 256, 256, 0, stream>>>(Wq, Wb, H_ * H_ / 4);
  cvt_bf16_k<<<(H_ * H_ / 4 + 255) / 256, 256, 0, stream>>>(Wk, Wb + H_ * H_, H_ * H_ / 4);
  cvt_bf16_k<<<(H_ * H_ / 4 + 255) / 256, 256, 0, stream>>>(Wv, Wb + 2 * H_ * H_, H_ * H_ / 4);

  qkv_gemm_k<<<dim3(8, 64, 3), 256, 0, stream>>>(Xb, Wb, bq, bk, bv, QKVh);

  attn_k<<<dim3(32, 64), 256, 0, stream>>>(QKVh, QKVh + (size_t)MROWS * H_,
                                           QKVh + (size_t)2 * MROWS * H_, mask, out);
}

// Round 2
// 348.560 us; speedup vs baseline: 1.1985x; 1.1985x over previous
//
#include <hip/hip_runtime.h>
#include <hip/hip_bf16.h>
#include <stdint.h>

#define NH 16
#define HD 64
#define H_ 1024
#define S_ 2048
#define B_ 4
#define MROWS 8192  // B_*S_

typedef __attribute__((ext_vector_type(4))) float f32x4;
typedef __attribute__((ext_vector_type(8))) short s16x8;

__device__ __forceinline__ unsigned short f2bf(float x) {
  unsigned int u = __float_as_uint(x);
  u += 0x7fffu + ((u >> 16) & 1u);
  return (unsigned short)(u >> 16);
}
__device__ __forceinline__ unsigned int pack_bf2(float lo, float hi) {
  return (unsigned int)f2bf(lo) | ((unsigned int)f2bf(hi) << 16);
}

__device__ __forceinline__ void ld_lds16(void* lds, const void* g) {
  __builtin_amdgcn_global_load_lds(
      (const __attribute__((address_space(1))) unsigned int*)g,
      (__attribute__((address_space(3))) unsigned int*)lds, 16, 0, 0);
}

// ---------------- fp32 -> bf16 conversion (vectorized) ----------------
__global__ void cvt_bf16_k(const float* __restrict__ src,
                           unsigned short* __restrict__ dst, int n4) {
  int i = blockIdx.x * blockDim.x + threadIdx.x;
  if (i >= n4) return;
  float4 v = reinterpret_cast<const float4*>(src)[i];
  ushort4 o;
  o.x = f2bf(v.x); o.y = f2bf(v.y); o.z = f2bf(v.z); o.w = f2bf(v.w);
  reinterpret_cast<ushort4*>(dst)[i] = o;
}

// ---------------- fused QKV projection GEMM ----------------
// Q,K out: [bh][s][d] bf16.  V out: [bh][d][s] bf16 (transposed for attn PV).
// 128x128 tile, BK=32, 4 waves (2x2), 16x16x32 bf16 MFMA, global_load_lds staging.
__global__ __launch_bounds__(256) void qkv_gemm_k(
    const unsigned short* __restrict__ Xb,   // [8192][1024] bf16
    const unsigned short* __restrict__ Wb,   // [3][1024][1024] bf16 (row n, col k)
    const float* __restrict__ bq, const float* __restrict__ bk,
    const float* __restrict__ bv,
    unsigned short* __restrict__ outAll) {
  __shared__ unsigned short As[128 * 32];
  __shared__ unsigned short Bs[128 * 32];
  int z = blockIdx.z;
  const unsigned short* Wp = Wb + (size_t)z * (H_ * H_);
  const float* bias = (z == 0) ? bq : (z == 1) ? bk : bv;
  unsigned short* outp = outAll + (size_t)z * ((size_t)MROWS * H_);
  int m0 = blockIdx.y * 128, n0 = blockIdx.x * 128;
  int tid = threadIdx.x;
  int w = tid >> 6, l = tid & 63;
  int wr = w >> 1, wc = w & 1;
  int g = l >> 4, ln = l & 15;
  f32x4 acc[4][4] = {};
  for (int k0 = 0; k0 < H_; k0 += 32) {
    __syncthreads();
#pragma unroll
    for (int a = 0; a < 2; ++a) {
      int ci = (w * 2 + a) * 64 + l;        // 16B chunk id (of 512)
      int row = ci >> 2, c = ci & 3;        // 4 chunks per 64B row
      ld_lds16(&As[(w * 2 + a) * 512], &Xb[(size_t)(m0 + row) * H_ + k0 + c * 8]);
      ld_lds16(&Bs[(w * 2 + a) * 512], &Wp[(size_t)(n0 + row) * H_ + k0 + c * 8]);
    }
    __syncthreads();
    s16x8 aF[4], bF[4];
#pragma unroll
    for (int mi = 0; mi < 4; ++mi)
      aF[mi] = *reinterpret_cast<const s16x8*>(&As[(wr * 64 + mi * 16 + ln) * 32 + 8 * g]);
#pragma unroll
    for (int ni = 0; ni < 4; ++ni)
      bF[ni] = *reinterpret_cast<const s16x8*>(&Bs[(wc * 64 + ni * 16 + ln) * 32 + 8 * g]);
#pragma unroll
    for (int mi = 0; mi < 4; ++mi)
#pragma unroll
      for (int ni = 0; ni < 4; ++ni)
        acc[mi][ni] = __builtin_amdgcn_mfma_f32_16x16x32_bf16(aF[mi], bF[ni], acc[mi][ni], 0, 0, 0);
  }
  // epilogue: bias add, bf16 store. Q/K -> [bh][s][d]; V -> [bh][d][s].
#pragma unroll
  for (int ni = 0; ni < 4; ++ni) {
    int ncol = n0 + wc * 64 + ni * 16 + ln;
    float bvv = bias[ncol];
    int h = ncol >> 6, d = ncol & 63;
#pragma unroll
    for (int mi = 0; mi < 4; ++mi) {
#pragma unroll
      for (int j = 0; j < 4; ++j) {
        int m = m0 + wr * 64 + mi * 16 + 4 * g + j;
        int b = m >> 11, s = m & 2047;
        unsigned short val = f2bf(acc[mi][ni][j] + bvv);
        if (z == 2)
          outp[((size_t)((b << 4) + h) * HD + d) * S_ + s] = val;
        else
          outp[((size_t)((b << 4) + h) * S_ + s) * HD + d] = val;
      }
    }
  }
}

// ---------------- flash attention ----------------
// grid (S/64, B*NH); 256 thr = 4 waves, each wave owns 16 q-rows.
// Swapped QK^T: S^T = mfma(K_frag, Q^T_frag) -> lane's softmax row q = lane&15.
// V arrives pre-transposed ([bh][d][s]) so all LDS staging is vector b128.
// T14 async-stage: next tile's global loads issue before this tile's compute.
__global__ __launch_bounds__(256) void attn_k(
    const unsigned short* __restrict__ Qh, const unsigned short* __restrict__ Kh,
    const unsigned short* __restrict__ Vtg, const float* __restrict__ mask,
    float* __restrict__ out) {
  __shared__ unsigned short Ks[64 * 72];       // [key][d] padded (+8) rows
  __shared__ unsigned short Vs[64 * 72];       // [d][key] padded rows (already transposed)
  __shared__ unsigned short Pl[4 * 16 * 72];   // per-wave P, [q][key] padded
  __shared__ float maskS[64];
  int bh = blockIdx.y;
  int b = bh >> 4, h = bh & 15;
  int tid = threadIdx.x;
  int w = tid >> 6, l = tid & 63;
  int g = l >> 4, ln = l & 15;
  int qbase = blockIdx.x * 64 + w * 16;
  const unsigned short* Qp = Qh + ((size_t)bh * S_ + qbase + ln) * HD;
  s16x8 qf[2];
  qf[0] = *reinterpret_cast<const s16x8*>(Qp + 8 * g);
  qf[1] = *reinterpret_cast<const s16x8*>(Qp + 32 + 8 * g);
  float m_run = -INFINITY, l_run = 0.0f;
  f32x4 ctx[4] = {};
  unsigned short* Pw = &Pl[w * 16 * 72];
  const size_t kvbase = (size_t)bh * S_ * HD;

  // staging coords: thread covers chunks tid and tid+256 of the 64x64 tile
  int r0 = tid >> 3, c0 = tid & 7;           // rows 0..31
  int r1 = r0 + 32;                          // rows 32..63
  s16x8 kreg[2], vreg[2];
  {
    kreg[0] = *reinterpret_cast<const s16x8*>(&Kh[kvbase + (size_t)r0 * HD + c0 * 8]);
    kreg[1] = *reinterpret_cast<const s16x8*>(&Kh[kvbase + (size_t)r1 * HD + c0 * 8]);
    vreg[0] = *reinterpret_cast<const s16x8*>(&Vtg[kvbase + (size_t)r0 * S_ + c0 * 8]);
    vreg[1] = *reinterpret_cast<const s16x8*>(&Vtg[kvbase + (size_t)r1 * S_ + c0 * 8]);
  }

  for (int k0 = 0; k0 < S_; k0 += 64) {
    __syncthreads();  // previous tile's compute done reading LDS
    *reinterpret_cast<s16x8*>(&Ks[r0 * 72 + c0 * 8]) = kreg[0];
    *reinterpret_cast<s16x8*>(&Ks[r1 * 72 + c0 * 8]) = kreg[1];
    *reinterpret_cast<s16x8*>(&Vs[r0 * 72 + c0 * 8]) = vreg[0];
    *reinterpret_cast<s16x8*>(&Vs[r1 * 72 + c0 * 8]) = vreg[1];
    if (tid < 64) maskS[tid] = mask[b * S_ + k0 + tid];
    if (k0 + 64 < S_) {  // issue next tile's loads; latency hides under compute
      kreg[0] = *reinterpret_cast<const s16x8*>(&Kh[kvbase + (size_t)(k0 + 64 + r0) * HD + c0 * 8]);
      kreg[1] = *reinterpret_cast<const s16x8*>(&Kh[kvbase + (size_t)(k0 + 64 + r1) * HD + c0 * 8]);
      vreg[0] = *reinterpret_cast<const s16x8*>(&Vtg[kvbase + (size_t)r0 * S_ + k0 + 64 + c0 * 8]);
      vreg[1] = *reinterpret_cast<const s16x8*>(&Vtg[kvbase + (size_t)r1 * S_ + k0 + 64 + c0 * 8]);
    }
    __syncthreads();

    // ---- QK^T (S^T): rows = keys, cols = q ----
    f32x4 sacc[4] = {};
#pragma unroll
    for (int ks = 0; ks < 2; ++ks) {
#pragma unroll
      for (int mt = 0; mt < 4; ++mt) {
        s16x8 kf = *reinterpret_cast<const s16x8*>(&Ks[(mt * 16 + ln) * 72 + ks * 32 + 8 * g]);
        sacc[mt] = __builtin_amdgcn_mfma_f32_16x16x32_bf16(kf, qf[ks], sacc[mt], 0, 0, 0);
      }
    }
    // ---- softmax for this lane's q (= ln); lane holds keys mt*16+4g+r ----
    float p[4][4];
    float mymax = -INFINITY;
#pragma unroll
    for (int mt = 0; mt < 4; ++mt)
#pragma unroll
      for (int r = 0; r < 4; ++r) {
        float v = sacc[mt][r] * 0.125f + maskS[mt * 16 + 4 * g + r];
        p[mt][r] = v;
        mymax = fmaxf(mymax, v);
      }
    mymax = fmaxf(mymax, __shfl_xor(mymax, 16));
    mymax = fmaxf(mymax, __shfl_xor(mymax, 32));
    float m_new = fmaxf(m_run, mymax);
    float alpha = __expf(m_run - m_new);
    float sum = 0.0f;
#pragma unroll
    for (int mt = 0; mt < 4; ++mt)
#pragma unroll
      for (int r = 0; r < 4; ++r) {
        float e = __expf(p[mt][r] - m_new);
        p[mt][r] = e;
        sum += e;
      }
    sum += __shfl_xor(sum, 16);
    sum += __shfl_xor(sum, 32);
    l_run = l_run * alpha + sum;
    m_run = m_new;
    // ---- write P (bf16 pairs) to wave-local LDS: key = 16mt+4g+2rp(+1) ----
#pragma unroll
    for (int mt = 0; mt < 4; ++mt)
#pragma unroll
      for (int rp = 0; rp < 2; ++rp)
        *reinterpret_cast<unsigned int*>(&Pw[ln * 72 + mt * 16 + 4 * g + 2 * rp]) =
            pack_bf2(p[mt][2 * rp], p[mt][2 * rp + 1]);
    // ---- rescale ctx (ctx rows q' = 4g+r; alpha lives at lane ln'=q') ----
    float resc[4];
#pragma unroll
    for (int r = 0; r < 4; ++r)
      resc[r] = __shfl(alpha, (l & 48) + 4 * g + r);
#pragma unroll
    for (int nt = 0; nt < 4; ++nt)
#pragma unroll
      for (int r = 0; r < 4; ++r) ctx[nt][r] *= resc[r];
    // ---- PV: ctx[q][d] += P[q][key] * V^T[d][key] ----
#pragma unroll
    for (int ks = 0; ks < 2; ++ks) {
      s16x8 pa = *reinterpret_cast<const s16x8*>(&Pw[ln * 72 + ks * 32 + 8 * g]);
#pragma unroll
      for (int nt = 0; nt < 4; ++nt) {
        s16x8 vf = *reinterpret_cast<const s16x8*>(&Vs[(nt * 16 + ln) * 72 + ks * 32 + 8 * g]);
        ctx[nt] = __builtin_amdgcn_mfma_f32_16x16x32_bf16(pa, vf, ctx[nt], 0, 0, 0);
      }
    }
  }
  // ---- normalize and store (coalesced along d) ----
  float inv[4];
#pragma unroll
  for (int r = 0; r < 4; ++r)
    inv[r] = 1.0f / __shfl(l_run, (l & 48) + 4 * g + r);
#pragma unroll
  for (int nt = 0; nt < 4; ++nt) {
#pragma unroll
    for (int r = 0; r < 4; ++r) {
      int q = qbase + 4 * g + r;
      out[((size_t)(b * S_ + q)) * H_ + h * HD + nt * 16 + ln] = ctx[nt][r] * inv[r];
    }
  }
}

extern "C" void kernel_launch(void* const* d_in, const int* in_sizes, int n_in,
                              void* d_out, int out_size, void* d_ws, size_t ws_size,
                              hipStream_t stream) {
  (void)in_sizes; (void)n_in; (void)out_size; (void)ws_size;
  const float* hs = (const float*)d_in[0];
  const float* mask = (const float*)d_in[1];
  const float* Wq = (const float*)d_in[2];
  const float* bq = (const float*)d_in[3];
  const float* Wk = (const float*)d_in[4];
  const float* bk = (const float*)d_in[5];
  const float* Wv = (const float*)d_in[6];
  const float* bv = (const float*)d_in[7];
  float* out = (float*)d_out;

  unsigned short* Xb = (unsigned short*)d_ws;                  // 8M bf16
  unsigned short* Wb = Xb + (size_t)MROWS * H_;                // 3M bf16
  unsigned short* QKVh = Wb + (size_t)3 * H_ * H_;             // 3 x 8M bf16

  cvt_bf16_k<<<(MROWS * H_ / 4 + 255) / 256, 256, 0, stream>>>(hs, Xb, MROWS * H_ / 4);
  cvt_bf16_k<<<(H_ * H_ / 4 + 255) / 256, 256, 0, stream>>>(Wq, Wb, H_ * H_ / 4);
  cvt_bf16_k<<<(H_ * H_ / 4 + 255) / 256, 256, 0, stream>>>(Wk, Wb + H_ * H_, H_ * H_ / 4);
  cvt_bf16_k<<<(H_ * H_ / 4 + 255) / 256, 256, 0, stream>>>(Wv, Wb + 2 * H_ * H_, H_ * H_ / 4);

  qkv_gemm_k<<<dim3(8, 64, 3), 256, 0, stream>>>(Xb, Wb, bq, bk, bv, QKVh);

  attn_k<<<dim3(32, 64), 256, 0, stream>>>(QKVh, QKVh + (size_t)MROWS * H_,
                                           QKVh + (size_t)2 * MROWS * H_, mask, out);
}